// Round 17
// baseline (18.218 us; speedup 1.0000x reference)
//
#include <hip/hip_runtime.h>
#include <math.h>

// Effective math (cross-attn K/V rows identical per batch element ->
// softmax uniform -> ctx == v; self-attn and QK paths are dead):
//   x   = im_repr @ ca_wv + ca_bv                  [256,768]
//   h   = gelu(x @ fi_w1 + fi_b1)  (exact erf)     [256,256]
//   y   = x + h @ fi_w2 + fi_b2                    [256,768]
//   out = LN(y) * ln_g + ln_b
//
// Round-17: kB prefetch depth 16 (64 VGPRs in flight) + hoisted gam/bet
// loads; kA unchanged except w2-pack spread over all 128 idle threads.

#define DMODEL 768
#define ENCD   128
#define HID    256
#define KC     4
#define KW     192   // kA k-slice width (DMODEL / KC)

// ws layout (float elements)
#define WS_X   0            // x   [256][768] f32
#define WS_P   196608       // p   [4][256][256] f32
#define WS_W2Q 458752       // w2q [32][768] uint4 (8 bf16 along k each)

__device__ __forceinline__ float gelu_exact(float v) {
    return 0.5f * v * (1.f + erff(v * 0.70710678118654752f));
}
__device__ __forceinline__ unsigned short f2bf(float f) {
    unsigned u = __float_as_uint(f);
    u = (u + 0x7FFFu + ((u >> 16) & 1u)) >> 16;   // RNE
    return (unsigned short)u;
}
__device__ __forceinline__ float bflo(unsigned u) { return __uint_as_float(u << 16); }
__device__ __forceinline__ float bfhi(unsigned u) { return __uint_as_float(u & 0xFFFF0000u); }
__device__ __forceinline__ unsigned packbf(float a, float b) {
    return (unsigned)f2bf(a) | ((unsigned)f2bf(b) << 16);
}

// ---- kA: grid(4 kc, 64 rowquads) x 512 thr ----
__global__ __launch_bounds__(512) void kA(
    const float* __restrict__ im,   // [256,128]
    const float* __restrict__ wv,   // [128,768]
    const float* __restrict__ bv,   // [768]
    const float* __restrict__ w1,   // [768,256]
    const float* __restrict__ w2,   // [256,768]
    float* __restrict__ ws)
{
    __shared__ float im_s[4][ENCD];
    __shared__ float xp[8][4][KW];    // stage1 e-slice partials
    __shared__ float x_s[4][KW];
    __shared__ float php[8][4][HID];  // stage2 k-slice partials
    const int t  = threadIdx.x;
    const int kc = blockIdx.x;
    const int r0 = blockIdx.y * 4;

    im_s[t >> 7][t & 127] = im[(r0 + (t >> 7)) * ENCD + (t & 127)];
    __syncthreads();

    // ---- stage 1 (t<384) + w2 pack on t in [384,512) ----
    if (t < 384) {
        const int q = t % 48, s = t / 48;
        const int colg = kc * KW + 4 * q;
        const int e0 = s * 16;
        float4 a0 = {0,0,0,0}, a1 = {0,0,0,0}, a2 = {0,0,0,0}, a3 = {0,0,0,0};
        #pragma unroll 8
        for (int e = e0; e < e0 + 16; ++e) {
            const float4 w = *(const float4*)(wv + e * DMODEL + colg);
            const float i0 = im_s[0][e], i1 = im_s[1][e];
            const float i2 = im_s[2][e], i3 = im_s[3][e];
            a0.x += i0 * w.x; a0.y += i0 * w.y; a0.z += i0 * w.z; a0.w += i0 * w.w;
            a1.x += i1 * w.x; a1.y += i1 * w.y; a1.z += i1 * w.z; a1.w += i1 * w.w;
            a2.x += i2 * w.x; a2.y += i2 * w.y; a2.z += i2 * w.z; a2.w += i2 * w.w;
            a3.x += i3 * w.x; a3.y += i3 * w.y; a3.z += i3 * w.z; a3.w += i3 * w.w;
        }
        ((float4*)xp[s][0])[q] = a0;
        ((float4*)xp[s][1])[q] = a1;
        ((float4*)xp[s][2])[q] = a2;
        ((float4*)xp[s][3])[q] = a3;
    } else {
        // 96 quads over 128 threads: 3 quads per 4 threads
        const int u = t - 384;                 // 0..127
        if ((u & 3) < 3) {
            const int local = (u >> 2) * 3 + (u & 3);  // 0..95
            const int qid = (blockIdx.y * KC + kc) * 96 + local;
            const int k8 = qid / DMODEL, col = qid % DMODEL;
            const float* src = w2 + (8 * k8) * DMODEL + col;
            uint4 uq;
            uq.x = packbf(src[0],          src[DMODEL]);
            uq.y = packbf(src[2 * DMODEL], src[3 * DMODEL]);
            uq.z = packbf(src[4 * DMODEL], src[5 * DMODEL]);
            uq.w = packbf(src[6 * DMODEL], src[7 * DMODEL]);
            ((uint4*)(ws + WS_W2Q))[qid] = uq;
        }
    }
    __syncthreads();

    if (t < KW) {
        const int colg = kc * KW + t;
        const float b = bv[colg];
        #pragma unroll
        for (int r = 0; r < 4; ++r) {
            float v = b;
            #pragma unroll
            for (int s = 0; s < 8; ++s) v += xp[s][r][t];
            ws[WS_X + (r0 + r) * DMODEL + colg] = v;
            x_s[r][t] = v;
        }
    }
    __syncthreads();

    // ---- stage 2: j-quad jq = t&63, k-slice ks = t>>6 (24 k each) ----
    {
        const int jq = t & 63, ks = t >> 6;
        const int k0 = ks * 24;
        float4 a0 = {0,0,0,0}, a1 = {0,0,0,0}, a2 = {0,0,0,0}, a3 = {0,0,0,0};
        const float* w1c = w1 + (size_t)kc * KW * HID;
        #pragma unroll 8
        for (int kk = 0; kk < 24; ++kk) {
            const int k = k0 + kk;
            const float4 w = *(const float4*)(w1c + k * HID + 4 * jq);
            const float x0 = x_s[0][k], x1 = x_s[1][k];
            const float x2 = x_s[2][k], x3 = x_s[3][k];
            a0.x += x0 * w.x; a0.y += x0 * w.y; a0.z += x0 * w.z; a0.w += x0 * w.w;
            a1.x += x1 * w.x; a1.y += x1 * w.y; a1.z += x1 * w.z; a1.w += x1 * w.w;
            a2.x += x2 * w.x; a2.y += x2 * w.y; a2.z += x2 * w.z; a2.w += x2 * w.w;
            a3.x += x3 * w.x; a3.y += x3 * w.y; a3.z += x3 * w.z; a3.w += x3 * w.w;
        }
        ((float4*)php[ks][0])[jq] = a0;
        ((float4*)php[ks][1])[jq] = a1;
        ((float4*)php[ks][2])[jq] = a2;
        ((float4*)php[ks][3])[jq] = a3;
    }
    __syncthreads();

    if (t < HID) {
        float* p = ws + WS_P + kc * (256 * HID);
        #pragma unroll
        for (int r = 0; r < 4; ++r) {
            float v = 0.f;
            #pragma unroll
            for (int s = 0; s < 8; ++s) v += php[s][r][t];
            p[(r0 + r) * HID + t] = v;
        }
    }
}

// ---- kB: 1 row/block, uint4 bf16 w2, prefetch depth 16, in-block LN ----
__global__ __launch_bounds__(768) void kB(
    const float* __restrict__ b1,   // [256]
    const float* __restrict__ b2,   // [768]
    const float* __restrict__ gam,  // [768]
    const float* __restrict__ bet,  // [768]
    const float* __restrict__ ws,
    float* __restrict__ out)        // [256,768]
{
    __shared__ float h_s[HID];
    __shared__ float red[12][2];
    const int t = threadIdx.x, r = blockIdx.x;

    // prefetch (independent of h): 16 w2q quads + x + b2 + gam/bet
    const uint4* w2q = (const uint4*)(ws + WS_W2Q);
    uint4 pf[16];
    #pragma unroll
    for (int i = 0; i < 16; ++i) pf[i] = w2q[i * DMODEL + t];
    const float xv  = ws[WS_X + r * DMODEL + t];
    const float b2v = b2[t];
    const float gv  = gam[t];
    const float btv = bet[t];

    if (t < HID) {
        const float* p = ws + WS_P;
        float v = b1[t];
        #pragma unroll
        for (int kc = 0; kc < KC; ++kc)
            v += p[kc * (256 * HID) + r * HID + t];
        h_s[t] = gelu_exact(v);
    }
    __syncthreads();

    float a0 = 0.f, a1 = 0.f, a2 = 0.f, a3 = 0.f;
    #define PROC(U, J)                                                  \
        a0 += h_s[(J) + 0] * bflo(U.x); a1 += h_s[(J) + 1] * bfhi(U.x); \
        a2 += h_s[(J) + 2] * bflo(U.y); a3 += h_s[(J) + 3] * bfhi(U.y); \
        a0 += h_s[(J) + 4] * bflo(U.z); a1 += h_s[(J) + 5] * bfhi(U.z); \
        a2 += h_s[(J) + 6] * bflo(U.w); a3 += h_s[(J) + 7] * bfhi(U.w);
    #pragma unroll
    for (int i = 0; i < 16; ++i) { PROC(pf[i], 8 * i) }
    #pragma unroll 4
    for (int k8 = 16; k8 < 32; ++k8) {
        uint4 u = w2q[k8 * DMODEL + t];
        PROC(u, 8 * k8)
    }
    #undef PROC
    const float y = xv + b2v + ((a0 + a1) + (a2 + a3));

    // LayerNorm across 12 waves
    float s = y, q = y * y;
    #pragma unroll
    for (int off = 32; off > 0; off >>= 1) {
        s += __shfl_down(s, off);
        q += __shfl_down(q, off);
    }
    const int lane = t & 63, wave = t >> 6;
    if (lane == 0) { red[wave][0] = s; red[wave][1] = q; }
    __syncthreads();

    float ss = 0.f, qq = 0.f;
    #pragma unroll
    for (int w = 0; w < 12; ++w) { ss += red[w][0]; qq += red[w][1]; }
    const float mu   = ss * (1.f / DMODEL);
    const float rstd = rsqrtf(qq * (1.f / DMODEL) - mu * mu + 1e-12f);

    out[r * DMODEL + t] = (y - mu) * rstd * gv + btv;
}

extern "C" void kernel_launch(void* const* d_in, const int* in_sizes, int n_in,
                              void* d_out, int out_size, void* d_ws, size_t ws_size,
                              hipStream_t stream) {
    const float* im  = (const float*)d_in[0];   // im_repr [256,128]
    const float* wv  = (const float*)d_in[13];  // ca_wv   [128,768]
    const float* bv  = (const float*)d_in[14];  // ca_bv   [768]
    const float* w1  = (const float*)d_in[16];  // fi_w1   [768,256]
    const float* b1  = (const float*)d_in[17];  // fi_b1   [256]
    const float* w2  = (const float*)d_in[18];  // fi_w2   [256,768]
    const float* b2  = (const float*)d_in[19];  // fi_b2   [768]
    const float* g   = (const float*)d_in[20];  // ln_g    [768]
    const float* bt  = (const float*)d_in[21];  // ln_b    [768]
    float* out = (float*)d_out;
    float* ws  = (float*)d_ws;

    kA<<<dim3(KC, 64), 512, 0, stream>>>(im, wv, bv, w1, w2, ws);
    kB<<<dim3(256),    768, 0, stream>>>(b1, b2, g, bt, ws, out);
}

// Round 18
// 18.013 us; speedup vs baseline: 1.0114x; 1.0114x over previous
//
#include <hip/hip_runtime.h>
#include <math.h>

// Effective math (cross-attn K/V rows identical per batch element ->
// softmax uniform -> ctx == v; self-attn and QK paths are dead):
//   x   = im_repr @ ca_wv + ca_bv                  [256,768]
//   h   = gelu(x @ fi_w1 + fi_b1)  (exact erf)     [256,256]
//   y   = x + h @ fi_w2 + fi_b2                    [256,768]
//   out = LN(y) * ln_g + ln_b
//
// Round-18: exact revert to R16 (best measured 17.6 us). R17's deeper
// prefetch (16) regressed via VGPR pressure; depth 8 is the sweet spot.

#define DMODEL 768
#define ENCD   128
#define HID    256
#define KC     4
#define KW     192   // kA k-slice width (DMODEL / KC)

// ws layout (float elements)
#define WS_X   0            // x   [256][768] f32
#define WS_P   196608       // p   [4][256][256] f32
#define WS_W2Q 458752       // w2q [32][768] uint4 (8 bf16 along k each)

__device__ __forceinline__ float gelu_exact(float v) {
    return 0.5f * v * (1.f + erff(v * 0.70710678118654752f));
}
__device__ __forceinline__ unsigned short f2bf(float f) {
    unsigned u = __float_as_uint(f);
    u = (u + 0x7FFFu + ((u >> 16) & 1u)) >> 16;   // RNE
    return (unsigned short)u;
}
__device__ __forceinline__ float bflo(unsigned u) { return __uint_as_float(u << 16); }
__device__ __forceinline__ float bfhi(unsigned u) { return __uint_as_float(u & 0xFFFF0000u); }
__device__ __forceinline__ unsigned packbf(float a, float b) {
    return (unsigned)f2bf(a) | ((unsigned)f2bf(b) << 16);
}

// ---- kA: grid(4 kc, 64 rowquads) x 512 thr ----
__global__ __launch_bounds__(512) void kA(
    const float* __restrict__ im,   // [256,128]
    const float* __restrict__ wv,   // [128,768]
    const float* __restrict__ bv,   // [768]
    const float* __restrict__ w1,   // [768,256]
    const float* __restrict__ w2,   // [256,768]
    float* __restrict__ ws)
{
    __shared__ float im_s[4][ENCD];
    __shared__ float xp[8][4][KW];    // stage1 e-slice partials (24 KB)
    __shared__ float x_s[4][KW];
    __shared__ float php[8][4][HID];  // stage2 k-slice partials (32 KB)
    const int t  = threadIdx.x;
    const int kc = blockIdx.x;
    const int r0 = blockIdx.y * 4;

    // im rows: 512 threads = exactly 4x128
    im_s[t >> 7][t & 127] = im[(r0 + (t >> 7)) * ENCD + (t & 127)];
    __syncthreads();

    // ---- stage 1 (t<384): col-quad q = t%48, e-slice s = t/48 (16 e each)
    //      pack    (384<=t<480): one w2q uint4 each (96/block) ----
    if (t < 384) {
        const int q = t % 48, s = t / 48;
        const int colg = kc * KW + 4 * q;
        const int e0 = s * 16;
        float4 a0 = {0,0,0,0}, a1 = {0,0,0,0}, a2 = {0,0,0,0}, a3 = {0,0,0,0};
        #pragma unroll 8
        for (int e = e0; e < e0 + 16; ++e) {
            const float4 w = *(const float4*)(wv + e * DMODEL + colg);
            const float i0 = im_s[0][e], i1 = im_s[1][e];
            const float i2 = im_s[2][e], i3 = im_s[3][e];
            a0.x += i0 * w.x; a0.y += i0 * w.y; a0.z += i0 * w.z; a0.w += i0 * w.w;
            a1.x += i1 * w.x; a1.y += i1 * w.y; a1.z += i1 * w.z; a1.w += i1 * w.w;
            a2.x += i2 * w.x; a2.y += i2 * w.y; a2.z += i2 * w.z; a2.w += i2 * w.w;
            a3.x += i3 * w.x; a3.y += i3 * w.y; a3.z += i3 * w.z; a3.w += i3 * w.w;
        }
        ((float4*)xp[s][0])[q] = a0;
        ((float4*)xp[s][1])[q] = a1;
        ((float4*)xp[s][2])[q] = a2;
        ((float4*)xp[s][3])[q] = a3;
    } else if (t < 480) {
        const int qid = (blockIdx.y * KC + kc) * 96 + (t - 384);  // [0,24576)
        const int k8 = qid / DMODEL, col = qid % DMODEL;
        const float* src = w2 + (8 * k8) * DMODEL + col;
        uint4 u;
        u.x = packbf(src[0],          src[DMODEL]);
        u.y = packbf(src[2 * DMODEL], src[3 * DMODEL]);
        u.z = packbf(src[4 * DMODEL], src[5 * DMODEL]);
        u.w = packbf(src[6 * DMODEL], src[7 * DMODEL]);
        ((uint4*)(ws + WS_W2Q))[qid] = u;
    }
    __syncthreads();

    // combine stage-1 partials
    if (t < KW) {
        const int colg = kc * KW + t;
        const float b = bv[colg];
        #pragma unroll
        for (int r = 0; r < 4; ++r) {
            float v = b;
            #pragma unroll
            for (int s = 0; s < 8; ++s) v += xp[s][r][t];
            ws[WS_X + (r0 + r) * DMODEL + colg] = v;
            x_s[r][t] = v;
        }
    }
    __syncthreads();

    // ---- stage 2: j-quad jq = t&63, k-slice ks = t>>6 (24 k each) ----
    {
        const int jq = t & 63, ks = t >> 6;
        const int k0 = ks * 24;
        float4 a0 = {0,0,0,0}, a1 = {0,0,0,0}, a2 = {0,0,0,0}, a3 = {0,0,0,0};
        const float* w1c = w1 + (size_t)kc * KW * HID;
        #pragma unroll 8
        for (int kk = 0; kk < 24; ++kk) {
            const int k = k0 + kk;
            const float4 w = *(const float4*)(w1c + k * HID + 4 * jq);
            const float x0 = x_s[0][k], x1 = x_s[1][k];
            const float x2 = x_s[2][k], x3 = x_s[3][k];
            a0.x += x0 * w.x; a0.y += x0 * w.y; a0.z += x0 * w.z; a0.w += x0 * w.w;
            a1.x += x1 * w.x; a1.y += x1 * w.y; a1.z += x1 * w.z; a1.w += x1 * w.w;
            a2.x += x2 * w.x; a2.y += x2 * w.y; a2.z += x2 * w.z; a2.w += x2 * w.w;
            a3.x += x3 * w.x; a3.y += x3 * w.y; a3.z += x3 * w.z; a3.w += x3 * w.w;
        }
        ((float4*)php[ks][0])[jq] = a0;
        ((float4*)php[ks][1])[jq] = a1;
        ((float4*)php[ks][2])[jq] = a2;
        ((float4*)php[ks][3])[jq] = a3;
    }
    __syncthreads();

    if (t < HID) {
        float* p = ws + WS_P + kc * (256 * HID);
        #pragma unroll
        for (int r = 0; r < 4; ++r) {
            float v = 0.f;
            #pragma unroll
            for (int s = 0; s < 8; ++s) v += php[s][r][t];
            p[(r0 + r) * HID + t] = v;
        }
    }
}

// ---- kB: 1 row/block, uint4 bf16 w2 with prefetch, in-block LN ----
__global__ __launch_bounds__(768) void kB(
    const float* __restrict__ b1,   // [256]
    const float* __restrict__ b2,   // [768]
    const float* __restrict__ gam,  // [768]
    const float* __restrict__ bet,  // [768]
    const float* __restrict__ ws,
    float* __restrict__ out)        // [256,768]
{
    __shared__ float h_s[HID];
    __shared__ float red[12][2];
    const int t = threadIdx.x, r = blockIdx.x;

    // prefetch (independent of h): first 8 w2q quads + x + b2
    const uint4* w2q = (const uint4*)(ws + WS_W2Q);
    uint4 u0 = w2q[0 * DMODEL + t];
    uint4 u1 = w2q[1 * DMODEL + t];
    uint4 u2 = w2q[2 * DMODEL + t];
    uint4 u3 = w2q[3 * DMODEL + t];
    uint4 u4 = w2q[4 * DMODEL + t];
    uint4 u5 = w2q[5 * DMODEL + t];
    uint4 u6 = w2q[6 * DMODEL + t];
    uint4 u7 = w2q[7 * DMODEL + t];
    const float xv  = ws[WS_X + r * DMODEL + t];
    const float b2v = b2[t];

    if (t < HID) {
        const float* p = ws + WS_P;
        float v = b1[t];
        #pragma unroll
        for (int kc = 0; kc < KC; ++kc)
            v += p[kc * (256 * HID) + r * HID + t];
        h_s[t] = gelu_exact(v);
    }
    __syncthreads();

    float a0 = 0.f, a1 = 0.f, a2 = 0.f, a3 = 0.f;
    #define PROC(U, J)                                                  \
        a0 += h_s[(J) + 0] * bflo(U.x); a1 += h_s[(J) + 1] * bfhi(U.x); \
        a2 += h_s[(J) + 2] * bflo(U.y); a3 += h_s[(J) + 3] * bfhi(U.y); \
        a0 += h_s[(J) + 4] * bflo(U.z); a1 += h_s[(J) + 5] * bfhi(U.z); \
        a2 += h_s[(J) + 6] * bflo(U.w); a3 += h_s[(J) + 7] * bfhi(U.w);
    PROC(u0, 0)  PROC(u1, 8)  PROC(u2, 16) PROC(u3, 24)
    PROC(u4, 32) PROC(u5, 40) PROC(u6, 48) PROC(u7, 56)
    #pragma unroll 4
    for (int k8 = 8; k8 < 32; ++k8) {
        uint4 u = w2q[k8 * DMODEL + t];
        const int j = 8 * k8;
        PROC(u, j)
    }
    #undef PROC
    const float y = xv + b2v + ((a0 + a1) + (a2 + a3));

    // LayerNorm across 12 waves
    float s = y, q = y * y;
    #pragma unroll
    for (int off = 32; off > 0; off >>= 1) {
        s += __shfl_down(s, off);
        q += __shfl_down(q, off);
    }
    const int lane = t & 63, wave = t >> 6;
    if (lane == 0) { red[wave][0] = s; red[wave][1] = q; }
    __syncthreads();

    float ss = 0.f, qq = 0.f;
    #pragma unroll
    for (int w = 0; w < 12; ++w) { ss += red[w][0]; qq += red[w][1]; }
    const float mu   = ss * (1.f / DMODEL);
    const float rstd = rsqrtf(qq * (1.f / DMODEL) - mu * mu + 1e-12f);

    out[r * DMODEL + t] = (y - mu) * rstd * gam[t] + bet[t];
}

extern "C" void kernel_launch(void* const* d_in, const int* in_sizes, int n_in,
                              void* d_out, int out_size, void* d_ws, size_t ws_size,
                              hipStream_t stream) {
    const float* im  = (const float*)d_in[0];   // im_repr [256,128]
    const float* wv  = (const float*)d_in[13];  // ca_wv   [128,768]
    const float* bv  = (const float*)d_in[14];  // ca_bv   [768]
    const float* w1  = (const float*)d_in[16];  // fi_w1   [768,256]
    const float* b1  = (const float*)d_in[17];  // fi_b1   [256]
    const float* w2  = (const float*)d_in[18];  // fi_w2   [256,768]
    const float* b2  = (const float*)d_in[19];  // fi_b2   [768]
    const float* g   = (const float*)d_in[20];  // ln_g    [768]
    const float* bt  = (const float*)d_in[21];  // ln_b    [768]
    float* out = (float*)d_out;
    float* ws  = (float*)d_ws;

    kA<<<dim3(KC, 64), 512, 0, stream>>>(im, wv, bv, w1, w2, ws);
    kB<<<dim3(256),    768, 0, stream>>>(b1, b2, g, bt, ws, out);
}